// Round 2
// baseline (197.178 us; speedup 1.0000x reference)
//
#include <hip/hip_runtime.h>
#include <stdint.h>

#define B_  64
#define T_  256
#define C_  384
#define H_  6
#define D_  64
#define NTOK (B_*T_)   // 16384

typedef float f32x4 __attribute__((ext_vector_type(4)));
typedef short s16x8 __attribute__((ext_vector_type(8)));

__device__ __forceinline__ unsigned short f2bf(float f) {
    unsigned int u;
    __builtin_memcpy(&u, &f, 4);
    u = u + 0x7FFFu + ((u >> 16) & 1u);   // RNE
    return (unsigned short)(u >> 16);
}

// ---------------------------------------------------------------------------
// Kernel 0a: convert x (f32) -> bf16, 4 elems/thread.
// ---------------------------------------------------------------------------
__global__ __launch_bounds__(256) void convert_x(
    const float* __restrict__ x, unsigned short* __restrict__ xb) {
    int i = (blockIdx.x * 256 + threadIdx.x) * 4;
    float4 v = *reinterpret_cast<const float4*>(x + i);
    ushort4 o;
    o.x = f2bf(v.x); o.y = f2bf(v.y); o.z = f2bf(v.z); o.w = f2bf(v.w);
    *reinterpret_cast<ushort4*>(xb + i) = o;
}

// ---------------------------------------------------------------------------
// Kernel 0b: convert + transpose weights f32 [R][Cc] -> bf16 [Cc][R] so GEMM
// B-fragments read contiguous-k 16B chunks.  z<18: per-(proj,head) 384x64;
// z==18: Wp 384x384.
// ---------------------------------------------------------------------------
__global__ __launch_bounds__(256) void transpose_weights(
    const float* __restrict__ Wq, const float* __restrict__ Wk,
    const float* __restrict__ Wv, const float* __restrict__ Wp,
    unsigned short* __restrict__ WTq, unsigned short* __restrict__ WTk,
    unsigned short* __restrict__ WTv, unsigned short* __restrict__ WTp) {
    __shared__ float tile[32][33];
    int z = blockIdx.y;
    const float* in;
    unsigned short* out;
    int R, Cc;
    if (z < 18) {
        int proj = z / 6, h = z % 6;
        const float* Wsrc = proj == 0 ? Wq : (proj == 1 ? Wk : Wv);
        unsigned short* Wdst = proj == 0 ? WTq : (proj == 1 ? WTk : WTv);
        in = Wsrc + h * C_ * D_;
        out = Wdst + h * C_ * D_;
        R = C_; Cc = D_;
    } else {
        in = Wp; out = WTp; R = C_; Cc = C_;
    }
    int tilesC = Cc / 32;
    int tilesR = R / 32;
    int bx = blockIdx.x;
    if (bx >= tilesC * tilesR) return;
    int tr = bx / tilesC, tc = bx % tilesC;
    int tx = threadIdx.x & 31;
    int ty8 = threadIdx.x >> 5;  // 0..7
    int gx = tc * 32 + tx;
#pragma unroll
    for (int i = 0; i < 4; i++) {
        int gy = tr * 32 + ty8 + i * 8;
        tile[ty8 + i * 8][tx] = in[gy * Cc + gx];
    }
    __syncthreads();
#pragma unroll
    for (int i = 0; i < 4; i++) {
        int oy = tc * 32 + ty8 + i * 8;  // output row = original col
        int ox = tr * 32 + tx;           // output col = original row
        out[oy * R + ox] = f2bf(tile[tx][ty8 + i * 8]);
    }
}

// ---------------------------------------------------------------------------
// Kernel 1: QKV projection GEMM (bf16 MFMA).  grid (256 m-tiles, 18).
// 64x64 output tile, 4 waves x (16 rows x 64 cols), K-step 32.
// A-frags straight from global xb (16B); B^T tile staged in LDS (pad 40).
// q,k stored [B,T,384] bf16; v stored transposed [B,H,D,T] bf16.
// ---------------------------------------------------------------------------
__global__ __launch_bounds__(256) void gemm_qkv(
    const unsigned short* __restrict__ X,
    const unsigned short* __restrict__ WTq, const unsigned short* __restrict__ WTk,
    const unsigned short* __restrict__ WTv,
    unsigned short* __restrict__ qws, unsigned short* __restrict__ kws,
    unsigned short* __restrict__ vTws) {
    __shared__ alignas(16) unsigned short bt[64 * 40];
    int m0 = blockIdx.x * 64;
    int zz = blockIdx.y;
    int proj = zz / H_;
    int h = zz % H_;
    const unsigned short* WT = proj == 0 ? WTq : (proj == 1 ? WTk : WTv);
    int tid = threadIdx.x;
    int w = tid >> 6, lane = tid & 63;
    int n16 = lane & 15, q4 = lane >> 4;

    f32x4 acc[4];
#pragma unroll
    for (int i = 0; i < 4; i++) acc[i] = (f32x4){0.f, 0.f, 0.f, 0.f};

    int stg_n = tid >> 2;              // 0..63
    int stg_k = (tid & 3) * 8;         // 0,8,16,24
    const unsigned short* wt_src = WT + (h * 64 + stg_n) * C_ + stg_k;
    unsigned short* bt_dst = &bt[stg_n * 40 + stg_k];
    const unsigned short* a_ptr = X + (m0 + w * 16 + n16) * C_ + q4 * 8;

    for (int k0 = 0; k0 < C_; k0 += 32) {
        __syncthreads();
        *reinterpret_cast<uint4*>(bt_dst) =
            *reinterpret_cast<const uint4*>(wt_src + k0);
        __syncthreads();
        s16x8 a = *reinterpret_cast<const s16x8*>(a_ptr + k0);
#pragma unroll
        for (int ct = 0; ct < 4; ct++) {
            s16x8 b = *reinterpret_cast<const s16x8*>(&bt[(ct * 16 + n16) * 40 + q4 * 8]);
            acc[ct] = __builtin_amdgcn_mfma_f32_16x16x32_bf16(a, b, acc[ct], 0, 0, 0);
        }
    }

    int row0 = m0 + w * 16 + q4 * 4;   // first of 4 consecutive token rows
    if (proj < 2) {
        unsigned short* outp = proj == 0 ? qws : kws;
#pragma unroll
        for (int ct = 0; ct < 4; ct++) {
            int col = h * 64 + ct * 16 + n16;
#pragma unroll
            for (int r = 0; r < 4; r++)
                outp[(row0 + r) * C_ + col] = f2bf(acc[ct][r]);
        }
    } else {
        int b = row0 >> 8;
        int t = row0 & 255;
#pragma unroll
        for (int ct = 0; ct < 4; ct++) {
            int d = ct * 16 + n16;
            ushort4 pk;
            pk.x = f2bf(acc[ct][0]); pk.y = f2bf(acc[ct][1]);
            pk.z = f2bf(acc[ct][2]); pk.w = f2bf(acc[ct][3]);
            *reinterpret_cast<ushort4*>(&vTws[((b * H_ + h) * 64 + d) * T_ + t]) = pk;
        }
    }
}

// ---------------------------------------------------------------------------
// Kernel 2: causal flash attention (bf16 MFMA).  grid (4 row-groups, B*H).
// Wave w owns Q rows [rg*64 + w*16, +16).  s advances in steps of 32
// (two 16x16 S-tiles -> one K=32 P A-operand).  Online softmax, stats via
// quad shuffles.  P relayout through per-wave LDS (no barriers).
// NOTE: Ows may alias qws (each wave reads exactly the q rows it later
// writes, reads-before-writes within the wave) -> no __restrict__ here.
// ---------------------------------------------------------------------------
__global__ __launch_bounds__(256) void attn_fwd(
    const unsigned short* qws, const unsigned short* __restrict__ kws,
    const unsigned short* __restrict__ vTws, unsigned short* Ows) {
    __shared__ alignas(16) unsigned short p_lds[4][16 * 40];
    int rg = blockIdx.x;               // 0..3
    int bh = blockIdx.y;               // 0..383
    int b = bh / H_, h = bh % H_;
    int tid = threadIdx.x;
    int w = tid >> 6, lane = tid & 63;
    int n16 = lane & 15, q4 = lane >> 4;
    int t0 = rg * 64 + w * 16;

    const unsigned short* qbase = qws + (b * T_ + t0 + n16) * C_ + h * 64 + q4 * 8;
    s16x8 qa0 = *reinterpret_cast<const s16x8*>(qbase);
    s16x8 qa1 = *reinterpret_cast<const s16x8*>(qbase + 32);

    float m_r[4], l_r[4];
    f32x4 o[4];
#pragma unroll
    for (int r = 0; r < 4; r++) { m_r[r] = -3.0e38f; l_r[r] = 0.f; }
#pragma unroll
    for (int i = 0; i < 4; i++) o[i] = (f32x4){0.f, 0.f, 0.f, 0.f};

    const f32x4 zero4 = (f32x4){0.f, 0.f, 0.f, 0.f};
    unsigned short* pw = &p_lds[w][0];
    const unsigned short* vb_base0 = vTws + ((b * H_ + h) * 64 + n16) * T_ + q4 * 8;

    for (int s0 = 0; s0 < t0 + 16; s0 += 32) {
        const unsigned short* kb_base = kws + (b * T_ + s0 + n16) * C_ + h * 64 + q4 * 8;
        s16x8 kb00 = *reinterpret_cast<const s16x8*>(kb_base);
        s16x8 kb01 = *reinterpret_cast<const s16x8*>(kb_base + 32);
        s16x8 kb10 = *reinterpret_cast<const s16x8*>(kb_base + 16 * C_);
        s16x8 kb11 = *reinterpret_cast<const s16x8*>(kb_base + 16 * C_ + 32);

        f32x4 sv0 = __builtin_amdgcn_mfma_f32_16x16x32_bf16(qa0, kb00, zero4, 0, 0, 0);
        sv0 = __builtin_amdgcn_mfma_f32_16x16x32_bf16(qa1, kb01, sv0, 0, 0, 0);
        f32x4 sv1 = __builtin_amdgcn_mfma_f32_16x16x32_bf16(qa0, kb10, zero4, 0, 0, 0);
        sv1 = __builtin_amdgcn_mfma_f32_16x16x32_bf16(qa1, kb11, sv1, 0, 0, 0);

        float alpha[4], pv0[4], pv1[4];
#pragma unroll
        for (int r = 0; r < 4; r++) {
            int t = t0 + q4 * 4 + r;
            bool mA = (s0 + n16) <= t;
            bool mB = (s0 + 16 + n16) <= t;
            float vA = sv0[r] * 0.125f;
            float vB = sv1[r] * 0.125f;
            float rm = fmaxf(mA ? vA : -3.0e38f, mB ? vB : -3.0e38f);
            rm = fmaxf(rm, __shfl_xor(rm, 1));
            rm = fmaxf(rm, __shfl_xor(rm, 2));
            rm = fmaxf(rm, __shfl_xor(rm, 4));
            rm = fmaxf(rm, __shfl_xor(rm, 8));
            float mn = fmaxf(m_r[r], rm);
            float al = __expf(m_r[r] - mn);
            float pA = mA ? __expf(vA - mn) : 0.0f;
            float pB = mB ? __expf(vB - mn) : 0.0f;
            float rs = pA + pB;
            rs += __shfl_xor(rs, 1);
            rs += __shfl_xor(rs, 2);
            rs += __shfl_xor(rs, 4);
            rs += __shfl_xor(rs, 8);
            l_r[r] = l_r[r] * al + rs;
            m_r[r] = mn;
            alpha[r] = al;
            pv0[r] = pA; pv1[r] = pB;
        }
#pragma unroll
        for (int dt = 0; dt < 4; dt++)
#pragma unroll
            for (int r = 0; r < 4; r++)
                o[dt][r] *= alpha[r];

        // P: C-layout -> LDS -> A-layout (per-wave scratch, no barrier needed)
#pragma unroll
        for (int r = 0; r < 4; r++) {
            pw[(q4 * 4 + r) * 40 + n16] = f2bf(pv0[r]);
            pw[(q4 * 4 + r) * 40 + 16 + n16] = f2bf(pv1[r]);
        }
        s16x8 pa = *reinterpret_cast<const s16x8*>(&pw[n16 * 40 + q4 * 8]);

        const unsigned short* vb = vb_base0 + s0;
#pragma unroll
        for (int dt = 0; dt < 4; dt++) {
            s16x8 vbf = *reinterpret_cast<const s16x8*>(vb + dt * 16 * T_);
            o[dt] = __builtin_amdgcn_mfma_f32_16x16x32_bf16(pa, vbf, o[dt], 0, 0, 0);
        }
    }

    float linv[4];
#pragma unroll
    for (int r = 0; r < 4; r++) linv[r] = 1.0f / l_r[r];
#pragma unroll
    for (int dt = 0; dt < 4; dt++) {
        int col = h * 64 + dt * 16 + n16;
#pragma unroll
        for (int r = 0; r < 4; r++)
            Ows[(b * T_ + t0 + q4 * 4 + r) * C_ + col] = f2bf(o[dt][r] * linv[r]);
    }
}

// ---------------------------------------------------------------------------
// Kernel 3: output projection GEMM + bias -> f32 out.  grid (256, 6).
// ---------------------------------------------------------------------------
__global__ __launch_bounds__(256) void gemm_out(
    const unsigned short* __restrict__ A, const unsigned short* __restrict__ WTp,
    const float* __restrict__ bp, float* __restrict__ out) {
    __shared__ alignas(16) unsigned short bt[64 * 40];
    int m0 = blockIdx.x * 64;
    int n0 = blockIdx.y * 64;
    int tid = threadIdx.x;
    int w = tid >> 6, lane = tid & 63;
    int n16 = lane & 15, q4 = lane >> 4;

    f32x4 acc[4];
#pragma unroll
    for (int i = 0; i < 4; i++) acc[i] = (f32x4){0.f, 0.f, 0.f, 0.f};

    int stg_n = tid >> 2;
    int stg_k = (tid & 3) * 8;
    const unsigned short* wt_src = WTp + (n0 + stg_n) * C_ + stg_k;
    unsigned short* bt_dst = &bt[stg_n * 40 + stg_k];
    const unsigned short* a_ptr = A + (m0 + w * 16 + n16) * C_ + q4 * 8;

    for (int k0 = 0; k0 < C_; k0 += 32) {
        __syncthreads();
        *reinterpret_cast<uint4*>(bt_dst) =
            *reinterpret_cast<const uint4*>(wt_src + k0);
        __syncthreads();
        s16x8 a = *reinterpret_cast<const s16x8*>(a_ptr + k0);
#pragma unroll
        for (int ct = 0; ct < 4; ct++) {
            s16x8 b = *reinterpret_cast<const s16x8*>(&bt[(ct * 16 + n16) * 40 + q4 * 8]);
            acc[ct] = __builtin_amdgcn_mfma_f32_16x16x32_bf16(a, b, acc[ct], 0, 0, 0);
        }
    }

    int row0 = m0 + w * 16 + q4 * 4;
#pragma unroll
    for (int ct = 0; ct < 4; ct++) {
        int col = n0 + ct * 16 + n16;
        float bias = bp[col];
#pragma unroll
        for (int r = 0; r < 4; r++)
            out[(row0 + r) * C_ + col] = acc[ct][r] + bias;
    }
}

// ---------------------------------------------------------------------------
extern "C" void kernel_launch(void* const* d_in, const int* in_sizes, int n_in,
                              void* d_out, int out_size, void* d_ws, size_t ws_size,
                              hipStream_t stream) {
    const float* x  = (const float*)d_in[0];
    const float* Wq = (const float*)d_in[1];
    const float* Wk = (const float*)d_in[2];
    const float* Wv = (const float*)d_in[3];
    const float* Wp = (const float*)d_in[4];
    const float* bp = (const float*)d_in[5];
    float* out = (float*)d_out;

    char* ws = (char*)d_ws;
    size_t off = 0;
    auto alloc = [&](size_t bytes) -> unsigned short* {
        unsigned short* p = (unsigned short*)(ws + off);
        off += (bytes + 255) & ~(size_t)255;
        return p;
    };
    unsigned short* WTq = alloc((size_t)H_ * C_ * D_ * 2);
    unsigned short* WTk = alloc((size_t)H_ * C_ * D_ * 2);
    unsigned short* WTv = alloc((size_t)H_ * C_ * D_ * 2);
    unsigned short* WTp = alloc((size_t)C_ * C_ * 2);
    unsigned short* xb  = alloc((size_t)NTOK * C_ * 2);
    unsigned short* qws = alloc((size_t)NTOK * C_ * 2);
    unsigned short* kws = alloc((size_t)NTOK * C_ * 2);
    unsigned short* vTw = alloc((size_t)NTOK * C_ * 2);
    unsigned short* Ows = qws;   // safe alias: attn reads its q rows before writing O
    // total ~52 MB of ws

    convert_x<<<dim3(NTOK * C_ / 4 / 256), dim3(256), 0, stream>>>(x, xb);
    transpose_weights<<<dim3(144, 19), dim3(256), 0, stream>>>(
        Wq, Wk, Wv, Wp, WTq, WTk, WTv, WTp);
    gemm_qkv<<<dim3(NTOK / 64, 18), dim3(256), 0, stream>>>(
        xb, WTq, WTk, WTv, qws, kws, vTw);
    attn_fwd<<<dim3(4, B_ * H_), dim3(256), 0, stream>>>(
        qws, kws, vTw, Ows);
    gemm_out<<<dim3(NTOK / 64, 6), dim3(256), 0, stream>>>(
        Ows, WTp, bp, out);
}